// Round 14
// baseline (96.621 us; speedup 1.0000x reference)
//
#include <hip/hip_runtime.h>

#define BATCH 2048
#define ODIM 64
#define IDIM 64
#define MDIM 32

static constexpr float LOG2E = 1.4426950408889634f;

#if __has_builtin(__builtin_amdgcn_exp2f)
#define EXP2F(x) __builtin_amdgcn_exp2f(x)
#else
#define EXP2F(x) exp2f(x)
#endif

typedef float v2f __attribute__((ext_vector_type(2)));

// psi_m = A*2^{a(x-z_m)^2} = [A*2^{a z_m^2}] * Ebase * r^m,
//   Ebase = 2^{x(e1 x + e2)}, r = 2^{rc x};  e1=a, e2=-2a z0, rc=-2a dz.
// em_i = Ebase * P(r),  ev_i = Ebase^2 * Q(r^2); P,Q Horner (even/odd split).
// Coefficients wave-uniform -> s_load to SGPRs; hot loop = v_pk_fma only.
// i-range split across 2 blocks (partial sums combined via atomicAdd; the
// per-i clamp is wave-local so the split is exact).

// Prep: zero `out` (re-poisoned each replay) + coefficient quads + aux.
__global__ __launch_bounds__(256) void prep_kernel(
    const float* __restrict__ z, const float* __restrict__ q_mu,
    const float* __restrict__ q_log_var, const float* __restrict__ log_scale,
    const float* __restrict__ log_variance,
    float4* __restrict__ cmq, float4* __restrict__ aux, float4* __restrict__ outz)
{
    int qt = blockIdx.x * 256 + threadIdx.x;  // quad id in [0, O*I*16)

    // zero the 1 MiB output (65536 float4, exactly one per thread)
    outz[qt] = make_float4(0.f, 0.f, 0.f, 0.f);

    int oi = qt >> 4;
    int k  = qt & 15;
    int g  = oi * MDIM + 2 * k;

    float ls   = log_scale[oi];
    float lv   = log_variance[oi];
    float ell  = fmaxf(expf(ls), 0.1f);
    float ell2 = ell * ell;
    float vk   = fmaxf(expf(lv), 1e-5f);
    float denom = ell2 + 1e-6f;               // x_var is constant EPS_XVAR
    float A    = vk * sqrtf(ell2 / denom);
    float a    = -0.5f * LOG2E / denom;       // base-2 exponent scale

    float qm0 = q_mu[g],     qm1 = q_mu[g + 1];
    float qv0 = fmaxf(expf(q_log_var[g]),     1e-5f);
    float qv1 = fmaxf(expf(q_log_var[g + 1]), 1e-5f);
    float zm0 = z[g],        zm1 = z[g + 1];
    float w0  = exp2f(a * zm0 * zm0);
    float w1  = exp2f(a * zm1 * zm1);

    float4 c;
    c.x = A * qm0 * w0;                          // c1[2k]
    c.y = A * A * (qv0 + qm0 * qm0) * w0 * w0;   // c2[2k]
    c.z = A * qm1 * w1;                          // c1[2k+1]
    c.w = A * A * (qv1 + qm1 * qm1) * w1 * w1;   // c2[2k+1]
    cmq[qt] = c;

    if (k == 0) {
        float z0 = z[oi * MDIM + 0];
        float z1 = z[oi * MDIM + 1];
        float dz = z1 - z0;
        aux[oi] = make_float4(a, -2.0f * a * z0, -2.0f * a * dz, 0.0f);
    }
}

// Main: block = (o, btile, ihalf); 512 thr / 8 waves; wave w owns i in
// [ihalf*32 + 4w, ihalf*32 + 4w + 4); lane owns b-pair (2*lane, 2*lane+1).
__global__ __launch_bounds__(512, 8) void gpkan_main_kernel(
    const float* __restrict__ x, const float4* __restrict__ cmq,
    const float4* __restrict__ aux, float* __restrict__ out)
{
    const int o     = blockIdx.x & (ODIM - 1);
    const int btile = (blockIdx.x >> 6) & 15;
    const int ihalf = blockIdx.x >> 10;                       // 0..1
    const int tid   = threadIdx.x;
    const int lane  = tid & 63;
    const int wave  = __builtin_amdgcn_readfirstlane(tid >> 6); // 0..7
    const int b0    = btile * 128 + 2 * lane;
    const int i0    = ihalf * 32 + wave * 4;

    __shared__ float red[2][8][128];   // 8 KB, [em|ev][wave][b_local]

    // x row slices for the b-pair: 16 B each -> 2x global_load_dwordx4.
    const float4 ax = *(const float4*)(x + (size_t)b0 * IDIM + i0);
    const float4 bx = *(const float4*)(x + (size_t)(b0 + 1) * IDIM + i0);
    v2f xv[4];
    xv[0].x = ax.x; xv[0].y = bx.x;
    xv[1].x = ax.y; xv[1].y = bx.y;
    xv[2].x = ax.z; xv[2].y = bx.z;
    xv[3].x = ax.w; xv[3].y = bx.w;

    // Wave-uniform coefficient pointers -> compiler scalarizes to s_load.
    const float4* __restrict__ Cb = cmq + ((size_t)o * IDIM + i0) * 16;
    const float4* __restrict__ Ab = aux + o * IDIM + i0;

    v2f emt = {0.f, 0.f};
    v2f evt = {0.f, 0.f};

    #pragma unroll
    for (int ii = 0; ii < 4; ++ii) {
        const float4 Ax = Ab[ii];                 // s_load_dwordx4
        const v2f x2 = xv[ii];

        v2f e1 = {Ax.x, Ax.x}, e2 = {Ax.y, Ax.y}, rc = {Ax.z, Ax.z};

        v2f t = __builtin_elementwise_fma(e1, x2, e2) * x2;
        v2f Eb;
        Eb.x = EXP2F(t.x); Eb.y = EXP2F(t.y);
        v2f ur = rc * x2;
        v2f rr;
        rr.x = EXP2F(ur.x); rr.y = EXP2F(ur.y);

        v2f s = rr * rr;     // r^2  (P chains' arg)
        v2f u = s * s;       // r^4  (Q chains' arg)

        v2f Pe = {0.f, 0.f}, Po = {0.f, 0.f};
        v2f Qe = {0.f, 0.f}, Qo = {0.f, 0.f};

        const float4* C = Cb + ii * 16;           // wave-uniform s_loads
        #pragma unroll
        for (int k = 15; k >= 0; --k) {
            float4 c = C[k];   // {c1_2k, c2_2k, c1_2k+1, c2_2k+1} in SGPRs
            v2f c1e = {c.x, c.x}, c2e = {c.y, c.y};
            v2f c1o = {c.z, c.z}, c2o = {c.w, c.w};
            Pe = __builtin_elementwise_fma(Pe, s, c1e);
            Po = __builtin_elementwise_fma(Po, s, c1o);
            Qe = __builtin_elementwise_fma(Qe, u, c2e);
            Qo = __builtin_elementwise_fma(Qo, u, c2o);
        }

        v2f P = __builtin_elementwise_fma(rr, Po, Pe);   // P(r)
        v2f Q = __builtin_elementwise_fma(s,  Qo, Qe);   // Q(r^2)

        v2f em_i = Eb * P;
        v2f ev_i = (Eb * Eb) * Q;

        // clamp per (b,o,i), BEFORE the i-sum (wave-local -> split exact)
        v2f eps = {1e-6f, 1e-6f};
        v2f d   = __builtin_elementwise_fma(-em_i, em_i, ev_i);
        evt += __builtin_elementwise_max(d, eps);
        emt += em_i;
    }

    red[0][wave][2 * lane + 0] = emt.x;
    red[0][wave][2 * lane + 1] = emt.y;
    red[1][wave][2 * lane + 0] = evt.x;
    red[1][wave][2 * lane + 1] = evt.y;
    __syncthreads();

    if (tid < 256) {
        const int sel = tid >> 7;          // 0: means, 1: vars
        const int l   = tid & 127;
        float acc = 0.f;
        #pragma unroll
        for (int w = 0; w < 8; ++w) acc += red[sel][w][l];
        const int bb = btile * 128 + l;
        float* dst = (sel == 0) ? &out[bb * ODIM + o]
                                : &out[BATCH * ODIM + bb * ODIM + o];
        atomicAdd(dst, acc);               // 2 i-half blocks per address
    }
}

extern "C" void kernel_launch(void* const* d_in, const int* in_sizes, int n_in,
                              void* d_out, int out_size, void* d_ws, size_t ws_size,
                              hipStream_t stream) {
    const float* x            = (const float*)d_in[0];
    const float* z            = (const float*)d_in[1];
    const float* q_mu         = (const float*)d_in[2];
    const float* q_log_var    = (const float*)d_in[3];
    const float* log_scale    = (const float*)d_in[4];
    const float* log_variance = (const float*)d_in[5];
    float* out = (float*)d_out;

    // ws layout: cmq (O*I*16 float4 = 1 MiB) | aux (O*I float4 = 64 KiB)
    char* ws = (char*)d_ws;
    float4* cmq = (float4*)ws;
    float4* aux = (float4*)(ws + (size_t)ODIM * IDIM * 16 * sizeof(float4));

    prep_kernel<<<dim3(256), dim3(256), 0, stream>>>(
        z, q_mu, q_log_var, log_scale, log_variance, cmq, aux, (float4*)out);
    gpkan_main_kernel<<<dim3((BATCH / 128) * ODIM * 2), dim3(512), 0, stream>>>(
        x, cmq, aux, out);
}

// Round 15
// 80.863 us; speedup vs baseline: 1.1949x; 1.1949x over previous
//
#include <hip/hip_runtime.h>

#define BATCH 2048
#define ODIM 64
#define IDIM 64
#define MDIM 32

static constexpr float LOG2E = 1.4426950408889634f;

#if __has_builtin(__builtin_amdgcn_exp2f)
#define EXP2F(x) __builtin_amdgcn_exp2f(x)
#else
#define EXP2F(x) exp2f(x)
#endif

typedef float v2f __attribute__((ext_vector_type(2)));

// psi_m = A*2^{a(x-z_m)^2} = [A*2^{a z_m^2}] * Ebase * r^m,
//   Ebase = 2^{x(e1 x + e2)}, r = 2^{rc x};  e1=a, e2=-2a z0, rc=-2a dz.
// em_i = Ebase * P(r),  ev_i = Ebase^2 * Q(r^2); P,Q Horner (even/odd split).
// Coefficients are wave-uniform -> s_load into SGPRs; Horner loop issues only
// v_pk_fma_f32 (VOP3P takes the SGPR broadcast directly). No LDS in hot loop.

// Prep: coefficient quads {c1_2k, c2_2k, c1_2k+1, c2_2k+1} + per-(o,i) aux.
__global__ __launch_bounds__(256) void prep_kernel(
    const float* __restrict__ z, const float* __restrict__ q_mu,
    const float* __restrict__ q_log_var, const float* __restrict__ log_scale,
    const float* __restrict__ log_variance,
    float4* __restrict__ cmq, float4* __restrict__ aux)
{
    int qt = blockIdx.x * 256 + threadIdx.x;  // quad id in [0, O*I*16)
    int oi = qt >> 4;
    int k  = qt & 15;
    int g  = oi * MDIM + 2 * k;

    float ls   = log_scale[oi];
    float lv   = log_variance[oi];
    float ell  = fmaxf(expf(ls), 0.1f);
    float ell2 = ell * ell;
    float vk   = fmaxf(expf(lv), 1e-5f);
    float denom = ell2 + 1e-6f;               // x_var is constant EPS_XVAR
    float A    = vk * sqrtf(ell2 / denom);
    float a    = -0.5f * LOG2E / denom;       // base-2 exponent scale

    float qm0 = q_mu[g],     qm1 = q_mu[g + 1];
    float qv0 = fmaxf(expf(q_log_var[g]),     1e-5f);
    float qv1 = fmaxf(expf(q_log_var[g + 1]), 1e-5f);
    float zm0 = z[g],        zm1 = z[g + 1];
    float w0  = exp2f(a * zm0 * zm0);
    float w1  = exp2f(a * zm1 * zm1);

    float4 c;
    c.x = A * qm0 * w0;                          // c1[2k]
    c.y = A * A * (qv0 + qm0 * qm0) * w0 * w0;   // c2[2k]
    c.z = A * qm1 * w1;                          // c1[2k+1]
    c.w = A * A * (qv1 + qm1 * qm1) * w1 * w1;   // c2[2k+1]
    cmq[qt] = c;

    if (k == 0) {
        float z0 = z[oi * MDIM + 0];
        float z1 = z[oi * MDIM + 1];
        float dz = z1 - z0;
        aux[oi] = make_float4(a, -2.0f * a * z0, -2.0f * a * dz, 0.0f);
    }
}

// Main: block = one o x 128 b's (btile 0..15), 512 thr / 8 waves; wave w
// owns i in [8w, 8w+8); lane owns b-pair (2*lane, 2*lane+1) as <2 x float>.
// x is read DIRECTLY (row-slices x[b][i0..i0+8) are 32B contiguous ->
// 4x global_load_dwordx4 per thread; L2-resident).
__global__ __launch_bounds__(512, 8) void gpkan_main_kernel(
    const float* __restrict__ x, const float4* __restrict__ cmq,
    const float4* __restrict__ aux, float* __restrict__ out)
{
    const int o     = blockIdx.x & (ODIM - 1);
    const int btile = blockIdx.x >> 6;                        // 0..15
    const int tid   = threadIdx.x;
    const int lane  = tid & 63;
    const int wave  = __builtin_amdgcn_readfirstlane(tid >> 6); // 0..7
    const int b0    = btile * 128 + 2 * lane;
    const int i0    = wave * 8;

    __shared__ float red[2][8][128];   // 8 KB, [em|ev][wave][b_local]

    // Load the two 8-float row slices for this lane's b-pair.
    const float4* pA = (const float4*)(x + (size_t)b0 * IDIM + i0);
    const float4* pB = (const float4*)(x + (size_t)(b0 + 1) * IDIM + i0);
    float4 a0 = pA[0], a1 = pA[1];
    float4 bb0 = pB[0], bb1 = pB[1];

    v2f xv[8];
    xv[0].x = a0.x; xv[0].y = bb0.x;
    xv[1].x = a0.y; xv[1].y = bb0.y;
    xv[2].x = a0.z; xv[2].y = bb0.z;
    xv[3].x = a0.w; xv[3].y = bb0.w;
    xv[4].x = a1.x; xv[4].y = bb1.x;
    xv[5].x = a1.y; xv[5].y = bb1.y;
    xv[6].x = a1.z; xv[6].y = bb1.z;
    xv[7].x = a1.w; xv[7].y = bb1.w;

    // Wave-uniform coefficient pointers -> compiler scalarizes to s_load.
    const float4* __restrict__ Cb = cmq + ((size_t)o * IDIM + i0) * 16;
    const float4* __restrict__ Ab = aux + o * IDIM + i0;

    v2f emt = {0.f, 0.f};
    v2f evt = {0.f, 0.f};

    #pragma unroll
    for (int ii = 0; ii < 8; ++ii) {
        const float4 Ax = Ab[ii];                 // s_load_dwordx4
        const v2f x2 = xv[ii];

        v2f e1 = {Ax.x, Ax.x}, e2 = {Ax.y, Ax.y}, rc = {Ax.z, Ax.z};

        v2f t = __builtin_elementwise_fma(e1, x2, e2) * x2;
        v2f Eb;
        Eb.x = EXP2F(t.x); Eb.y = EXP2F(t.y);
        v2f ur = rc * x2;
        v2f rr;
        rr.x = EXP2F(ur.x); rr.y = EXP2F(ur.y);

        v2f s = rr * rr;     // r^2  (P chains' arg)
        v2f u = s * s;       // r^4  (Q chains' arg)

        v2f Pe = {0.f, 0.f}, Po = {0.f, 0.f};
        v2f Qe = {0.f, 0.f}, Qo = {0.f, 0.f};

        const float4* C = Cb + ii * 16;           // wave-uniform -> s_load_dwordx16
        #pragma unroll
        for (int k = 15; k >= 0; --k) {
            float4 c = C[k];   // {c1_2k, c2_2k, c1_2k+1, c2_2k+1} in SGPRs
            v2f c1e = {c.x, c.x}, c2e = {c.y, c.y};
            v2f c1o = {c.z, c.z}, c2o = {c.w, c.w};
            Pe = __builtin_elementwise_fma(Pe, s, c1e);
            Po = __builtin_elementwise_fma(Po, s, c1o);
            Qe = __builtin_elementwise_fma(Qe, u, c2e);
            Qo = __builtin_elementwise_fma(Qo, u, c2o);
        }

        v2f P = __builtin_elementwise_fma(rr, Po, Pe);   // P(r)
        v2f Q = __builtin_elementwise_fma(s,  Qo, Qe);   // Q(r^2)

        v2f em_i = Eb * P;
        v2f ev_i = (Eb * Eb) * Q;

        // clamp per (b,o,i), BEFORE the i-sum
        v2f eps = {1e-6f, 1e-6f};
        v2f d   = __builtin_elementwise_fma(-em_i, em_i, ev_i);
        evt += __builtin_elementwise_max(d, eps);
        emt += em_i;
    }

    red[0][wave][2 * lane + 0] = emt.x;
    red[0][wave][2 * lane + 1] = emt.y;
    red[1][wave][2 * lane + 0] = evt.x;
    red[1][wave][2 * lane + 1] = evt.y;
    __syncthreads();

    if (tid < 256) {
        const int sel = tid >> 7;          // 0: means, 1: vars
        const int l   = tid & 127;
        float acc = 0.f;
        #pragma unroll
        for (int w = 0; w < 8; ++w) acc += red[sel][w][l];
        const int bb = btile * 128 + l;
        if (sel == 0) out[bb * ODIM + o] = acc;                // edge_means.sum(2)
        else          out[BATCH * ODIM + bb * ODIM + o] = acc; // edge_vars.sum(2)
    }
}

extern "C" void kernel_launch(void* const* d_in, const int* in_sizes, int n_in,
                              void* d_out, int out_size, void* d_ws, size_t ws_size,
                              hipStream_t stream) {
    const float* x            = (const float*)d_in[0];
    const float* z            = (const float*)d_in[1];
    const float* q_mu         = (const float*)d_in[2];
    const float* q_log_var    = (const float*)d_in[3];
    const float* log_scale    = (const float*)d_in[4];
    const float* log_variance = (const float*)d_in[5];
    float* out = (float*)d_out;

    // ws layout: cmq (O*I*16 float4 = 1 MiB) | aux (O*I float4 = 64 KiB)
    char* ws = (char*)d_ws;
    float4* cmq = (float4*)ws;
    float4* aux = (float4*)(ws + (size_t)ODIM * IDIM * 16 * sizeof(float4));

    prep_kernel<<<dim3(256), dim3(256), 0, stream>>>(
        z, q_mu, q_log_var, log_scale, log_variance, cmq, aux);
    gpkan_main_kernel<<<dim3((BATCH / 128) * ODIM), dim3(512), 0, stream>>>(
        x, cmq, aux, out);
}